// Round 13
// baseline (1306.728 us; speedup 1.0000x reference)
//
#include <hip/hip_runtime.h>
#include <math.h>

#define NSIG 32768
#define KD   512
#define ED   64
#define SP   5

// ---------------- prologue: DtD(f64) + DtDf(f32) + zero coefOut ----------------
__global__ __launch_bounds__(256) void k_pre(const float* __restrict__ D,
                                             double* __restrict__ DtD,
                                             float* __restrict__ DtDf,
                                             float4* __restrict__ coef4) {
  if (blockIdx.x < 1024) {
    int flat = blockIdx.x * 256 + threadIdx.x;   // 0..262143
    int i = flat >> 9, j = flat & 511;
    double acc = 0.0;
    #pragma unroll
    for (int e = 0; e < ED; ++e)
      acc += (double)D[e * KD + i] * (double)D[e * KD + j];
    if (i == j) acc += 1e-10;
    DtD[flat] = acc;
    DtDf[flat] = (float)acc;
  } else {
    size_t count4 = (size_t)KD * NSIG / 4;
    size_t i = (size_t)(blockIdx.x - 1024) * 256 + threadIdx.x;
    size_t stride = (size_t)2048 * 256;
    float4 zv = make_float4(0.f, 0.f, 0.f, 0.f);
    for (; i < count4; i += stride) coef4[i] = zv;
  }
}

// ---------------- fused kernel: f32 corr0 + f32 scan (f64-hedged) OMP ----------------
// CORR (f32): wave wv owns signals 2wv,2wv+1; lane l owns atoms {4l..4l+3} U
//   {256+4l..+3}; two float4 LDS reads per e-row (zero-conflict class, R8-verified).
// SCAN (f32 + top-2): group (wv,g) = signal 2wv+g; lane li owns atoms
//   {128*j4+4*li+bit}. Winner/runner-up reduced jointly; if gap < tau the group
//   redoes the scan in exact f64 (c0 recomputed from D,z) -> selection == pure-f64.
// Post-selection (f64, unchanged): Ginv triangle via Schur rank-1 (1 rcp/iter);
//   c0sel[K] = vb + sum_m DtD[ab,idx_m]*cc_m; cc_new = Ginv*c0sel - pad(cc_old).
template <int K>
__device__ __forceinline__ void omp_iter(const double* __restrict__ DtD,
                                         const float* __restrict__ DtDf,
                                         const float* __restrict__ Dg,
                                         const float* __restrict__ zbuf,
                                         int myS,
                                         const float (&c0f)[16], unsigned& amask,
                                         int (&idx)[SP], double (&cc)[SP],
                                         double (&tri)[15], double (&c0sel)[SP],
                                         int li) {
  float ccf[SP > 0 ? SP : 1];
  #pragma unroll
  for (int m = 0; m < K; ++m) ccf[m] = (float)cc[m];
  // ----- f32 masked scan with per-lane top-2 -----
  float v1 = -INFINITY, v2 = -INFINITY;
  int a1 = 0x7FFFFFFF;
  #pragma unroll
  for (int j4 = 0; j4 < 4; ++j4) {
    int a0 = (j4 << 7) + (li << 2);
    float gv[K > 0 ? K : 1][4];
    #pragma unroll
    for (int m = 0; m < K; ++m) {
      float4 q = *(const float4*)(DtDf + (size_t)idx[m] * KD + a0);
      gv[m][0] = q.x; gv[m][1] = q.y; gv[m][2] = q.z; gv[m][3] = q.w;
    }
    #pragma unroll
    for (int bit = 0; bit < 4; ++bit) {
      float v = c0f[4 * j4 + bit];
      #pragma unroll
      for (int m = 0; m < K; ++m) v -= gv[m][bit] * ccf[m];
      v = ((amask >> (4 * j4 + bit)) & 1u) ? -INFINITY : v;
      if (v > v1) { v2 = v1; v1 = v; a1 = a0 + bit; }   // atoms ascending:
      else v2 = fmaxf(v2, v);                           // strict > keeps smallest
    }
  }
  // ----- 32-lane top-2 merge (winner tie-break: smallest atom) -----
  #pragma unroll
  for (int s = 16; s >= 1; s >>= 1) {
    float ov1 = __shfl_xor(v1, s, 64);
    int   oa1 = __shfl_xor(a1, s, 64);
    float ov2 = __shfl_xor(v2, s, 64);
    bool oWins = (ov1 > v1) || (ov1 == v1 && oa1 < a1);
    float loserTop = oWins ? v1 : ov1;
    if (oWins) { v1 = ov1; a1 = oa1; }
    v2 = fmaxf(fmaxf(v2, ov2), loserTop);
  }
  int ab;
  double vbUse;
  float tau = 2e-3f * fmaxf(1.0f, fabsf(v1));
  if (v1 - v2 >= tau) {               // group-uniform fast path
    ab = a1;
    vbUse = (double)v1;
  } else {
    // ----- rare exact-f64 redo: recompute c0 and rescan (== pure-f64 kernel) -----
    double vbd = -INFINITY;
    int abd = 0x7FFFFFFF;
    #pragma unroll
    for (int j4 = 0; j4 < 4; ++j4) {
      #pragma unroll
      for (int bit = 0; bit < 4; ++bit) {
        int a = (j4 << 7) + (li << 2) + bit;
        double cv = 0.0;
        for (int e = 0; e < ED; ++e)
          cv += (double)Dg[e * KD + a] * (double)zbuf[e * 16 + myS];
        #pragma unroll
        for (int m = 0; m < K; ++m)
          cv -= DtD[(size_t)idx[m] * KD + a] * cc[m];
        cv = ((amask >> (4 * j4 + bit)) & 1u) ? -INFINITY : cv;
        if (cv > vbd) { vbd = cv; abd = a; }
      }
    }
    #pragma unroll
    for (int s = 16; s >= 1; s >>= 1) {
      double ov = __shfl_xor(vbd, s, 64);
      int    oa = __shfl_xor(abd, s, 64);
      if (ov > vbd || (ov == vbd && oa < abd)) { vbd = ov; abd = oa; }
    }
    ab = abd;
    vbUse = vbd;
  }
  idx[K] = ab;
  if (((ab >> 2) & 31) == li) amask |= 1u << ((((ab >> 7) << 2)) | (ab & 3));
  // ----- gather new Gram row (f64); rebuild c0sel via symmetry -----
  const double* drow = DtD + (size_t)ab * KD;
  double bb[SP], u[SP];
  #pragma unroll
  for (int m = 0; m < K; ++m) bb[m] = drow[idx[m]];
  {
    double csel = vbUse;
    #pragma unroll
    for (int m = 0; m < K; ++m) csel += bb[m] * cc[m];
    c0sel[K] = csel;
  }
  // ----- Schur rank-1 update of Ginv triangle -----
  double sch = drow[ab];
  #pragma unroll
  for (int i = 0; i < K; ++i) {
    double ui = 0.0;
    #pragma unroll
    for (int m = 0; m < K; ++m) {
      int lo = i < m ? i : m, hi = i < m ? m : i;
      ui += tri[lo * SP - lo * (lo + 1) / 2 + hi] * bb[m];
    }
    u[i] = ui;
    sch -= bb[i] * ui;
  }
  double r = 1.0 / sch;
  #pragma unroll
  for (int i = 0; i < K; ++i) {
    #pragma unroll
    for (int j = i; j < K; ++j) tri[i * SP - i * (i + 1) / 2 + j] += r * u[i] * u[j];
    tri[i * SP - i * (i + 1) / 2 + K] = -r * u[i];
  }
  tri[K * SP - K * (K + 1) / 2 + K] = r;
  // ----- h = Ginv_new * c0sel ; cc = h - pad(cc_old) -----
  double h[SP];
  #pragma unroll
  for (int i = 0; i <= K; ++i) {
    double s = 0.0;
    #pragma unroll
    for (int j = 0; j <= K; ++j) {
      int lo = i < j ? i : j, hi = i < j ? j : i;
      s += tri[lo * SP - lo * (lo + 1) / 2 + hi] * c0sel[j];
    }
    h[i] = s;
  }
  #pragma unroll
  for (int i = 0; i < K; ++i) cc[i] = h[i] - cc[i];
  cc[K] = h[K];
}

__global__ __launch_bounds__(512) void k_fused(const float* __restrict__ z,
                                               const float* __restrict__ D,
                                               const double* __restrict__ DtD,
                                               const float* __restrict__ DtDf,
                                               float* __restrict__ coefOut,
                                               int* __restrict__ idxWs,
                                               double* __restrict__ cWs,
                                               double* __restrict__ csumWs) {
  __shared__ float Dlds[2][8 * 512];   // 2 x 16 KB double-buffered 8-row D tiles
  __shared__ float zbuf[64 * 16];      // 4 KB [e][sig] for the block's 16 signals
  int tid = threadIdx.x;
  int lane = tid & 63;
  int wv = tid >> 6;                   // wave 0..7 -> signals 2wv, 2wv+1
  int li = lane & 31;
  int g  = lane >> 5;                  // scan group: signal 2wv+g
  int myS = 2 * wv + g;
  int n = blockIdx.x * 16 + myS;
  // ---- stage z: zbuf[e*16+sig] = z[b, e, p0+sig] ----
  {
    int n0 = blockIdx.x * 16;
    int b = n0 >> 10, p0 = n0 & 1023;
    const float* zb = z + (size_t)b * 65536 + p0;
    #pragma unroll
    for (int k2 = 0; k2 < 2; ++k2) {
      int f = tid + 512 * k2;
      zbuf[f] = zb[(f >> 4) * 1024 + (f & 15)];
    }
  }
  // ---- stage D tile 0, then double-buffered loop (issue-early) ----
  #pragma unroll
  for (int i = 0; i < 2; ++i) {
    const float* gp = D + i * 2048 + wv * 256 + lane * 4;
    float* lp = &Dlds[0][i * 2048 + wv * 256];
    __builtin_amdgcn_global_load_lds(
        (const __attribute__((address_space(1))) void*)gp,
        (__attribute__((address_space(3))) void*)lp, 16, 0, 0);
  }
  float cA[8], cB[8];
  #pragma unroll
  for (int p = 0; p < 8; ++p) { cA[p] = 0.0f; cB[p] = 0.0f; }
  for (int t8 = 0; t8 < 8; ++t8) {
    __syncthreads();   // drains gload_lds: buf[t8&1] ready; other free
    if (t8 < 7) {
      #pragma unroll
      for (int i = 0; i < 2; ++i) {
        const float* gp = D + (t8 + 1) * 4096 + i * 2048 + wv * 256 + lane * 4;
        float* lp = &Dlds[(t8 + 1) & 1][i * 2048 + wv * 256];
        __builtin_amdgcn_global_load_lds(
            (const __attribute__((address_space(1))) void*)gp,
            (__attribute__((address_space(3))) void*)lp, 16, 0, 0);
      }
    }
    const float* buf = Dlds[t8 & 1];
    #pragma unroll
    for (int e = 0; e < 8; ++e) {
      float2 zz = *(const float2*)(zbuf + (t8 * 8 + e) * 16 + 2 * wv);
      float zA = zz.x, zB = zz.y;
      const float* drow = buf + e * 512;
      float4 d0 = *(const float4*)(drow + lane * 4);         // atoms 4l..4l+3
      float4 d1 = *(const float4*)(drow + 256 + lane * 4);   // atoms 256+4l..+3
      float dv[8] = {d0.x, d0.y, d0.z, d0.w, d1.x, d1.y, d1.z, d1.w};
      #pragma unroll
      for (int p = 0; p < 8; ++p) {
        cA[p] += zA * dv[p];
        cB[p] += zB * dv[p];
      }
    }
  }
  // ---- exchange corr layout -> scan layout (f32) ----
  // c0f[4*j4+bit] = (g? cB:cA)[4*(j4>>1)+bit] held by lane 32*(j4&1)+li
  float c0f[16];
  #pragma unroll
  for (int j4 = 0; j4 < 4; ++j4) {
    int src = ((j4 & 1) << 5) + li;
    #pragma unroll
    for (int bit = 0; bit < 4; ++bit) {
      float tA = __shfl(cA[((j4 >> 1) << 2) + bit], src, 64);
      float tB = __shfl(cB[((j4 >> 1) << 2) + bit], src, 64);
      c0f[4 * j4 + bit] = g ? tB : tA;
    }
  }
  // ---- OMP iterations ----
  unsigned amask = 0;
  int idx[SP]; double cc[SP]; double tri[15]; double c0sel[SP];
  omp_iter<0>(DtD, DtDf, D, zbuf, myS, c0f, amask, idx, cc, tri, c0sel, li);
  omp_iter<1>(DtD, DtDf, D, zbuf, myS, c0f, amask, idx, cc, tri, c0sel, li);
  omp_iter<2>(DtD, DtDf, D, zbuf, myS, c0f, amask, idx, cc, tri, c0sel, li);
  omp_iter<3>(DtD, DtDf, D, zbuf, myS, c0f, amask, idx, cc, tri, c0sel, li);
  omp_iter<4>(DtD, DtDf, D, zbuf, myS, c0f, amask, idx, cc, tri, c0sel, li);
  if (li == 0) {
    double cs = 0.0;
    #pragma unroll
    for (int j = 0; j < SP; ++j) {
      double cj = cc[j];
      cj = fmin(fmax(cj, -10000000.0), 10000000.0);   // COEFF_CLAMP
      cs += fabs(cj);
      idxWs[n * SP + j] = idx[j];
      cWs[n * SP + j] = cj;
      coefOut[(size_t)idx[j] * NSIG + n] = (float)cj;
    }
    csumWs[n] = cs;
  }
}

// ---------------- kernel D: z_q + per-block rec-loss partials ----------------
__global__ __launch_bounds__(256) void k_zq(const float* __restrict__ z,
                                            const float* __restrict__ D,
                                            const int* __restrict__ idxWs,
                                            const double* __restrict__ cWs,
                                            float* __restrict__ zqOut,
                                            double* __restrict__ recWs) {
  int t = threadIdx.x;
  size_t flat = (size_t)blockIdx.x * 256 + t;   // indexes z / z_q directly
  int b = (int)(flat >> 16);
  int e = (int)((flat >> 10) & 63);
  int p = (int)(flat & 1023);
  int n = b * 1024 + p;
  double u = 0.0;
  #pragma unroll
  for (int j = 0; j < SP; ++j) {
    int a = idxWs[n * SP + j];
    u += (double)D[e * KD + a] * cWs[n * SP + j];
  }
  float zv = z[flat];
  double d = u - (double)zv;
  double dc = fmin(fmax(d, -1.0), 1.0);
  zqOut[flat] = (float)((double)zv + dc);
  __shared__ double red[256];
  red[t] = d * d;
  __syncthreads();
  #pragma unroll
  for (int s = 128; s >= 1; s >>= 1) {
    if (t < s) red[t] += red[t + s];
    __syncthreads();
  }
  if (t == 0) recWs[blockIdx.x] = red[0];
}

// ---------------- kernel E: deterministic final reduction -> loss ----------------
__global__ __launch_bounds__(256) void k_loss(const double* __restrict__ recWs,
                                              const double* __restrict__ csumWs,
                                              float* __restrict__ lossOut) {
  int t = threadIdx.x;
  double r = 0.0, c = 0.0;
  for (int i = t; i < 8192; i += 256) r += recWs[i];
  for (int i = t; i < NSIG; i += 256) c += csumWs[i];
  __shared__ double red[512];
  red[t] = r; red[256 + t] = c;
  __syncthreads();
  #pragma unroll
  for (int s = 128; s >= 1; s >>= 1) {
    if (t < s) { red[t] += red[t + s]; red[256 + t] += red[256 + t + s]; }
    __syncthreads();
  }
  if (t == 0) {
    double rec = red[0] / (double)(64.0 * 32768.0);
    double cm  = red[256] / (double)(512.0 * 32768.0);
    // loss = rec + 0.25*(1+5/10)*commit + 1e-3*coeff ; commit == rec numerically
    double loss = rec + 0.375 * rec + 0.001 * cm;
    lossOut[0] = (float)loss;
  }
}

extern "C" void kernel_launch(void* const* d_in, const int* in_sizes, int n_in,
                              void* d_out, int out_size, void* d_ws, size_t ws_size,
                              hipStream_t stream) {
  const float* z = (const float*)d_in[0];       // (32,64,32,32)
  const float* D = (const float*)d_in[1];       // (64,512)
  float* out = (float*)d_out;
  float* zqOut   = out;                         // 2097152
  float* lossOut = out + 2097152;               // 1
  float* coefOut = out + 2097153;               // 512*32768

  // workspace carve (all 8B-aligned offsets)
  char* w = (char*)d_ws;
  double* DtD    = (double*)w; w += (size_t)KD * KD * 8;        // 2 MB
  float*  DtDf   = (float*)w;  w += (size_t)KD * KD * 4;        // 1 MB
  int*    idxWs  = (int*)w;    w += (size_t)NSIG * SP * 4;      // 640 KB
  double* cWs    = (double*)w; w += (size_t)NSIG * SP * 8;      // 1.25 MB
  double* csumWs = (double*)w; w += (size_t)NSIG * 8;           // 256 KB
  double* recWs  = (double*)w; w += (size_t)8192 * 8;           // 64 KB

  k_pre<<<3072, 256, 0, stream>>>(D, DtD, DtDf, (float4*)coefOut);
  k_fused<<<NSIG / 16, 512, 0, stream>>>(z, D, DtD, DtDf, coefOut, idxWs, cWs, csumWs);
  k_zq<<<8192, 256, 0, stream>>>(z, D, idxWs, cWs, zqOut, recWs);
  k_loss<<<1, 256, 0, stream>>>(recWs, csumWs, lossOut);
}

// Round 16
// 339.258 us; speedup vs baseline: 3.8517x; 3.8517x over previous
//
#include <hip/hip_runtime.h>
#include <math.h>

#define NSIG 32768
#define KD   512
#define ED   64
#define SP   5

// ---------------- prologue: DtD(f64) + DtDf(f32) + zero coefOut ----------------
__global__ __launch_bounds__(256) void k_pre(const float* __restrict__ D,
                                             double* __restrict__ DtD,
                                             float* __restrict__ DtDf,
                                             float4* __restrict__ coef4) {
  if (blockIdx.x < 1024) {
    int flat = blockIdx.x * 256 + threadIdx.x;   // 0..262143
    int i = flat >> 9, j = flat & 511;
    double acc = 0.0;
    #pragma unroll
    for (int e = 0; e < ED; ++e)
      acc += (double)D[e * KD + i] * (double)D[e * KD + j];
    if (i == j) acc += 1e-10;
    DtD[flat] = acc;
    DtDf[flat] = (float)acc;
  } else {
    size_t count4 = (size_t)KD * NSIG / 4;
    size_t i = (size_t)(blockIdx.x - 1024) * 256 + threadIdx.x;
    size_t stride = (size_t)2048 * 256;
    float4 zv = make_float4(0.f, 0.f, 0.f, 0.f);
    for (; i < count4; i += stride) coef4[i] = zv;
  }
}

// ---------------- f64 OMP iteration (R11-exact; used by k_redo) ----------------
template <int K>
__device__ __forceinline__ void omp_iter64(const double* __restrict__ DtD,
                                           const double (&c0)[16], unsigned& amask,
                                           int (&idx)[SP], double (&cc)[SP],
                                           double (&tri)[15], double (&c0sel)[SP],
                                           int li) {
  double vb = -INFINITY;
  int ab = 0x7FFFFFFF;
  #pragma unroll
  for (int j4 = 0; j4 < 4; ++j4) {
    int a0 = (j4 << 7) + (li << 2);
    double v0 = c0[4 * j4], v1 = c0[4 * j4 + 1];
    double v2 = c0[4 * j4 + 2], v3 = c0[4 * j4 + 3];
    #pragma unroll
    for (int m = 0; m < K; ++m) {
      const double* gp = DtD + (size_t)idx[m] * KD + a0;
      double2 gA = *(const double2*)gp;
      double2 gB = *(const double2*)(gp + 2);
      v0 -= gA.x * cc[m];
      v1 -= gA.y * cc[m];
      v2 -= gB.x * cc[m];
      v3 -= gB.y * cc[m];
    }
    v0 = ((amask >> (4 * j4 + 0)) & 1u) ? -INFINITY : v0;
    v1 = ((amask >> (4 * j4 + 1)) & 1u) ? -INFINITY : v1;
    v2 = ((amask >> (4 * j4 + 2)) & 1u) ? -INFINITY : v2;
    v3 = ((amask >> (4 * j4 + 3)) & 1u) ? -INFINITY : v3;
    if (v0 > vb) { vb = v0; ab = a0; }
    if (v1 > vb) { vb = v1; ab = a0 + 1; }
    if (v2 > vb) { vb = v2; ab = a0 + 2; }
    if (v3 > vb) { vb = v3; ab = a0 + 3; }
  }
  #pragma unroll
  for (int s = 16; s >= 1; s >>= 1) {
    double ov = __shfl_xor(vb, s, 64);
    int    oa = __shfl_xor(ab, s, 64);
    if (ov > vb || (ov == vb && oa < ab)) { vb = ov; ab = oa; }
  }
  idx[K] = ab;
  if (((ab >> 2) & 31) == li) amask |= 1u << ((((ab >> 7) << 2)) | (ab & 3));
  const double* drow = DtD + (size_t)ab * KD;
  double bb[SP], u[SP];
  #pragma unroll
  for (int m = 0; m < K; ++m) bb[m] = drow[idx[m]];
  {
    double csel = vb;
    #pragma unroll
    for (int m = 0; m < K; ++m) csel += bb[m] * cc[m];
    c0sel[K] = csel;
  }
  double sch = drow[ab];
  #pragma unroll
  for (int i = 0; i < K; ++i) {
    double ui = 0.0;
    #pragma unroll
    for (int m = 0; m < K; ++m) {
      int lo = i < m ? i : m, hi = i < m ? m : i;
      ui += tri[lo * SP - lo * (lo + 1) / 2 + hi] * bb[m];
    }
    u[i] = ui;
    sch -= bb[i] * ui;
  }
  double r = 1.0 / sch;
  #pragma unroll
  for (int i = 0; i < K; ++i) {
    #pragma unroll
    for (int j = i; j < K; ++j) tri[i * SP - i * (i + 1) / 2 + j] += r * u[i] * u[j];
    tri[i * SP - i * (i + 1) / 2 + K] = -r * u[i];
  }
  tri[K * SP - K * (K + 1) / 2 + K] = r;
  double h[SP];
  #pragma unroll
  for (int i = 0; i <= K; ++i) {
    double s = 0.0;
    #pragma unroll
    for (int j = 0; j <= K; ++j) {
      int lo = i < j ? i : j, hi = i < j ? j : i;
      s += tri[lo * SP - lo * (lo + 1) / 2 + hi] * c0sel[j];
    }
    h[i] = s;
  }
  #pragma unroll
  for (int i = 0; i < K; ++i) cc[i] = h[i] - cc[i];
  cc[K] = h[K];
}

// ---------------- f32 OMP iteration with top-2 flag (fast path) ----------------
// f32 scan selects; near-ties (gap < tau) set redoFlag (resolved by k_redo).
// c0sel[K] computed EXACTLY in f64 via 32-lane parallel reduce of D.z -> the
// solve (f64 Schur/Ginv, unchanged) sees no f32 noise.
template <int K>
__device__ __forceinline__ void omp_iter32(const double* __restrict__ DtD,
                                           const float* __restrict__ DtDf,
                                           const float* __restrict__ Dg,
                                           const float* __restrict__ zbuf,
                                           int myS,
                                           const float (&c0f)[16], unsigned& amask,
                                           int (&idx)[SP], double (&cc)[SP],
                                           double (&tri)[15], double (&c0sel)[SP],
                                           int li, int& redoFlag) {
  float ccf[SP];
  #pragma unroll
  for (int m = 0; m < K; ++m) ccf[m] = (float)cc[m];
  // ----- f32 masked scan with per-lane top-2 -----
  float v1 = -INFINITY, v2 = -INFINITY;
  int a1 = 0x7FFFFFFF;
  #pragma unroll
  for (int j4 = 0; j4 < 4; ++j4) {
    int a0 = (j4 << 7) + (li << 2);
    float gv[SP][4];
    #pragma unroll
    for (int m = 0; m < K; ++m) {
      float4 q = *(const float4*)(DtDf + (size_t)idx[m] * KD + a0);
      gv[m][0] = q.x; gv[m][1] = q.y; gv[m][2] = q.z; gv[m][3] = q.w;
    }
    #pragma unroll
    for (int bit = 0; bit < 4; ++bit) {
      float v = c0f[4 * j4 + bit];
      #pragma unroll
      for (int m = 0; m < K; ++m) v -= gv[m][bit] * ccf[m];
      v = ((amask >> (4 * j4 + bit)) & 1u) ? -INFINITY : v;
      if (v > v1) { v2 = v1; v1 = v; a1 = a0 + bit; }   // ascending atoms:
      else v2 = fmaxf(v2, v);                           // strict > keeps smallest
    }
  }
  // ----- 32-lane top-2 merge (winner tie-break: smallest atom) -----
  #pragma unroll
  for (int s = 16; s >= 1; s >>= 1) {
    float ov1 = __shfl_xor(v1, s, 64);
    int   oa1 = __shfl_xor(a1, s, 64);
    float ov2 = __shfl_xor(v2, s, 64);
    bool oWins = (ov1 > v1) || (ov1 == v1 && oa1 < a1);
    float loserTop = oWins ? v1 : ov1;
    if (oWins) { v1 = ov1; a1 = oa1; }
    v2 = fmaxf(fmaxf(v2, ov2), loserTop);
  }
  float ccmax = 0.0f;
  #pragma unroll
  for (int m = 0; m < K; ++m) ccmax = fmaxf(ccmax, fabsf(ccf[m]));
  float tau = 1.5e-3f + 1e-4f * fabsf(v1) + 2e-4f * ccmax;
  if (!(v1 - v2 >= tau)) redoFlag = 1;   // near-tie (or NaN) -> exact redo later
  int ab = a1;
  idx[K] = ab;
  if (((ab >> 2) & 31) == li) amask |= 1u << ((((ab >> 7) << 2)) | (ab & 3));
  // ----- exact f64 c0sel[K] = <D[:,ab], z[:,myS]> via parallel reduce -----
  {
    int e0 = li << 1;
    double part = (double)Dg[e0 * KD + ab] * (double)zbuf[e0 * 16 + myS]
                + (double)Dg[(e0 + 1) * KD + ab] * (double)zbuf[(e0 + 1) * 16 + myS];
    #pragma unroll
    for (int s = 16; s >= 1; s >>= 1) part += __shfl_xor(part, s, 64);
    c0sel[K] = part;
  }
  // ----- f64 Gram gather + Schur rank-1 + solve (unchanged) -----
  const double* drow = DtD + (size_t)ab * KD;
  double bb[SP], u[SP];
  #pragma unroll
  for (int m = 0; m < K; ++m) bb[m] = drow[idx[m]];
  double sch = drow[ab];
  #pragma unroll
  for (int i = 0; i < K; ++i) {
    double ui = 0.0;
    #pragma unroll
    for (int m = 0; m < K; ++m) {
      int lo = i < m ? i : m, hi = i < m ? m : i;
      ui += tri[lo * SP - lo * (lo + 1) / 2 + hi] * bb[m];
    }
    u[i] = ui;
    sch -= bb[i] * ui;
  }
  double r = 1.0 / sch;
  #pragma unroll
  for (int i = 0; i < K; ++i) {
    #pragma unroll
    for (int j = i; j < K; ++j) tri[i * SP - i * (i + 1) / 2 + j] += r * u[i] * u[j];
    tri[i * SP - i * (i + 1) / 2 + K] = -r * u[i];
  }
  tri[K * SP - K * (K + 1) / 2 + K] = r;
  double h[SP];
  #pragma unroll
  for (int i = 0; i <= K; ++i) {
    double s = 0.0;
    #pragma unroll
    for (int j = 0; j <= K; ++j) {
      int lo = i < j ? i : j, hi = i < j ? j : i;
      s += tri[lo * SP - lo * (lo + 1) / 2 + hi] * c0sel[j];
    }
    h[i] = s;
  }
  #pragma unroll
  for (int i = 0; i < K; ++i) cc[i] = h[i] - cc[i];
  cc[K] = h[K];
}

// ---------------- fused kernel: f32 corr + f32 scan + f64 solve ----------------
__global__ __launch_bounds__(512) void k_fused(const float* __restrict__ z,
                                               const float* __restrict__ D,
                                               const double* __restrict__ DtD,
                                               const float* __restrict__ DtDf,
                                               float* __restrict__ coefOut,
                                               int* __restrict__ idxWs,
                                               double* __restrict__ cWs,
                                               double* __restrict__ csumWs,
                                               int* __restrict__ flagWs) {
  __shared__ float Dlds[2][8 * 512];   // 2 x 16 KB double-buffered 8-row D tiles
  __shared__ float zbuf[64 * 16];      // 4 KB [e][sig]
  int tid = threadIdx.x;
  int lane = tid & 63;
  int wv = tid >> 6;                   // wave 0..7 -> signals 2wv, 2wv+1
  int li = lane & 31;
  int g  = lane >> 5;
  int myS = 2 * wv + g;
  int n = blockIdx.x * 16 + myS;
  {
    int n0 = blockIdx.x * 16;
    int b = n0 >> 10, p0 = n0 & 1023;
    const float* zb = z + (size_t)b * 65536 + p0;
    #pragma unroll
    for (int k2 = 0; k2 < 2; ++k2) {
      int f = tid + 512 * k2;
      zbuf[f] = zb[(f >> 4) * 1024 + (f & 15)];
    }
  }
  #pragma unroll
  for (int i = 0; i < 2; ++i) {
    const float* gp = D + i * 2048 + wv * 256 + lane * 4;
    float* lp = &Dlds[0][i * 2048 + wv * 256];
    __builtin_amdgcn_global_load_lds(
        (const __attribute__((address_space(1))) void*)gp,
        (__attribute__((address_space(3))) void*)lp, 16, 0, 0);
  }
  float cA[8], cB[8];
  #pragma unroll
  for (int p = 0; p < 8; ++p) { cA[p] = 0.0f; cB[p] = 0.0f; }
  for (int t8 = 0; t8 < 8; ++t8) {
    __syncthreads();
    if (t8 < 7) {
      #pragma unroll
      for (int i = 0; i < 2; ++i) {
        const float* gp = D + (t8 + 1) * 4096 + i * 2048 + wv * 256 + lane * 4;
        float* lp = &Dlds[(t8 + 1) & 1][i * 2048 + wv * 256];
        __builtin_amdgcn_global_load_lds(
            (const __attribute__((address_space(1))) void*)gp,
            (__attribute__((address_space(3))) void*)lp, 16, 0, 0);
      }
    }
    const float* buf = Dlds[t8 & 1];
    #pragma unroll
    for (int e = 0; e < 8; ++e) {
      float2 zz = *(const float2*)(zbuf + (t8 * 8 + e) * 16 + 2 * wv);
      float zA = zz.x, zB = zz.y;
      const float* drow = buf + e * 512;
      float4 d0 = *(const float4*)(drow + lane * 4);
      float4 d1 = *(const float4*)(drow + 256 + lane * 4);
      float dv[8] = {d0.x, d0.y, d0.z, d0.w, d1.x, d1.y, d1.z, d1.w};
      #pragma unroll
      for (int p = 0; p < 8; ++p) {
        cA[p] += zA * dv[p];
        cB[p] += zB * dv[p];
      }
    }
  }
  // corr -> scan layout exchange (f32)
  float c0f[16];
  #pragma unroll
  for (int j4 = 0; j4 < 4; ++j4) {
    int src = ((j4 & 1) << 5) + li;
    #pragma unroll
    for (int bit = 0; bit < 4; ++bit) {
      float tA = __shfl(cA[((j4 >> 1) << 2) + bit], src, 64);
      float tB = __shfl(cB[((j4 >> 1) << 2) + bit], src, 64);
      c0f[4 * j4 + bit] = g ? tB : tA;
    }
  }
  unsigned amask = 0;
  int redoFlag = 0;
  int idx[SP]; double cc[SP]; double tri[15]; double c0sel[SP];
  omp_iter32<0>(DtD, DtDf, D, zbuf, myS, c0f, amask, idx, cc, tri, c0sel, li, redoFlag);
  omp_iter32<1>(DtD, DtDf, D, zbuf, myS, c0f, amask, idx, cc, tri, c0sel, li, redoFlag);
  omp_iter32<2>(DtD, DtDf, D, zbuf, myS, c0f, amask, idx, cc, tri, c0sel, li, redoFlag);
  omp_iter32<3>(DtD, DtDf, D, zbuf, myS, c0f, amask, idx, cc, tri, c0sel, li, redoFlag);
  omp_iter32<4>(DtD, DtDf, D, zbuf, myS, c0f, amask, idx, cc, tri, c0sel, li, redoFlag);
  if (li == 0) {
    double cs = 0.0;
    #pragma unroll
    for (int j = 0; j < SP; ++j) {
      double cj = cc[j];
      cj = fmin(fmax(cj, -10000000.0), 10000000.0);   // COEFF_CLAMP
      cs += fabs(cj);
      idxWs[n * SP + j] = idx[j];
      cWs[n * SP + j] = cj;
      coefOut[(size_t)idx[j] * NSIG + n] = (float)cj;
    }
    csumWs[n] = cs;
    flagWs[n] = redoFlag;
  }
}

// ---------------- redo kernel: exact-f64 OMP for flagged signals ----------------
__global__ __launch_bounds__(512) void k_redo(const float* __restrict__ z,
                                              const float* __restrict__ D,
                                              const double* __restrict__ DtD,
                                              const int* __restrict__ flagWs,
                                              float* __restrict__ coefOut,
                                              int* __restrict__ idxWs,
                                              double* __restrict__ cWs,
                                              double* __restrict__ csumWs) {
  int tid = threadIdx.x;
  int lane = tid & 63;
  int wv = tid >> 6;
  int li = lane & 31;
  int g  = lane >> 5;
  int n = blockIdx.x * 16 + 2 * wv + g;
  if (!flagWs[n]) return;                 // group-uniform; exec-mask divergence ok
  int b = n >> 10, p = n & 1023;
  const float* zp = z + (size_t)b * 65536 + p;
  // exact f64 c0, e-ascending per atom (bit-identical to the R11 pipeline)
  double c0[16];
  #pragma unroll
  for (int j = 0; j < 16; ++j) c0[j] = 0.0;
  for (int e = 0; e < ED; ++e) {
    double zv = (double)zp[e * 1024];
    #pragma unroll
    for (int j4 = 0; j4 < 4; ++j4) {
      float4 dv = *(const float4*)(D + e * KD + (j4 << 7) + (li << 2));
      c0[4 * j4 + 0] += zv * (double)dv.x;
      c0[4 * j4 + 1] += zv * (double)dv.y;
      c0[4 * j4 + 2] += zv * (double)dv.z;
      c0[4 * j4 + 3] += zv * (double)dv.w;
    }
  }
  unsigned amask = 0;
  int idx[SP]; double cc[SP]; double tri[15]; double c0sel[SP];
  omp_iter64<0>(DtD, c0, amask, idx, cc, tri, c0sel, li);
  omp_iter64<1>(DtD, c0, amask, idx, cc, tri, c0sel, li);
  omp_iter64<2>(DtD, c0, amask, idx, cc, tri, c0sel, li);
  omp_iter64<3>(DtD, c0, amask, idx, cc, tri, c0sel, li);
  omp_iter64<4>(DtD, c0, amask, idx, cc, tri, c0sel, li);
  if (li == 0) {
    // zero the f32-pass writes, then write exact results
    #pragma unroll
    for (int j = 0; j < SP; ++j)
      coefOut[(size_t)idxWs[n * SP + j] * NSIG + n] = 0.0f;
    double cs = 0.0;
    #pragma unroll
    for (int j = 0; j < SP; ++j) {
      double cj = cc[j];
      cj = fmin(fmax(cj, -10000000.0), 10000000.0);
      cs += fabs(cj);
      idxWs[n * SP + j] = idx[j];
      cWs[n * SP + j] = cj;
      coefOut[(size_t)idx[j] * NSIG + n] = (float)cj;
    }
    csumWs[n] = cs;
  }
}

// ---------------- kernel D: z_q + per-block rec-loss partials ----------------
__global__ __launch_bounds__(256) void k_zq(const float* __restrict__ z,
                                            const float* __restrict__ D,
                                            const int* __restrict__ idxWs,
                                            const double* __restrict__ cWs,
                                            float* __restrict__ zqOut,
                                            double* __restrict__ recWs) {
  int t = threadIdx.x;
  size_t flat = (size_t)blockIdx.x * 256 + t;
  int b = (int)(flat >> 16);
  int e = (int)((flat >> 10) & 63);
  int p = (int)(flat & 1023);
  int n = b * 1024 + p;
  double u = 0.0;
  #pragma unroll
  for (int j = 0; j < SP; ++j) {
    int a = idxWs[n * SP + j];
    u += (double)D[e * KD + a] * cWs[n * SP + j];
  }
  float zv = z[flat];
  double d = u - (double)zv;
  double dc = fmin(fmax(d, -1.0), 1.0);
  zqOut[flat] = (float)((double)zv + dc);
  __shared__ double red[256];
  red[t] = d * d;
  __syncthreads();
  #pragma unroll
  for (int s = 128; s >= 1; s >>= 1) {
    if (t < s) red[t] += red[t + s];
    __syncthreads();
  }
  if (t == 0) recWs[blockIdx.x] = red[0];
}

// ---------------- kernel E: deterministic final reduction -> loss ----------------
__global__ __launch_bounds__(256) void k_loss(const double* __restrict__ recWs,
                                              const double* __restrict__ csumWs,
                                              float* __restrict__ lossOut) {
  int t = threadIdx.x;
  double r = 0.0, c = 0.0;
  for (int i = t; i < 8192; i += 256) r += recWs[i];
  for (int i = t; i < NSIG; i += 256) c += csumWs[i];
  __shared__ double red[512];
  red[t] = r; red[256 + t] = c;
  __syncthreads();
  #pragma unroll
  for (int s = 128; s >= 1; s >>= 1) {
    if (t < s) { red[t] += red[t + s]; red[256 + t] += red[256 + t + s]; }
    __syncthreads();
  }
  if (t == 0) {
    double rec = red[0] / (double)(64.0 * 32768.0);
    double cm  = red[256] / (double)(512.0 * 32768.0);
    double loss = rec + 0.375 * rec + 0.001 * cm;
    lossOut[0] = (float)loss;
  }
}

extern "C" void kernel_launch(void* const* d_in, const int* in_sizes, int n_in,
                              void* d_out, int out_size, void* d_ws, size_t ws_size,
                              hipStream_t stream) {
  const float* z = (const float*)d_in[0];       // (32,64,32,32)
  const float* D = (const float*)d_in[1];       // (64,512)
  float* out = (float*)d_out;
  float* zqOut   = out;                         // 2097152
  float* lossOut = out + 2097152;               // 1
  float* coefOut = out + 2097153;               // 512*32768

  char* w = (char*)d_ws;
  double* DtD    = (double*)w; w += (size_t)KD * KD * 8;        // 2 MB
  float*  DtDf   = (float*)w;  w += (size_t)KD * KD * 4;        // 1 MB
  int*    idxWs  = (int*)w;    w += (size_t)NSIG * SP * 4;      // 640 KB
  double* cWs    = (double*)w; w += (size_t)NSIG * SP * 8;      // 1.25 MB
  double* csumWs = (double*)w; w += (size_t)NSIG * 8;           // 256 KB
  double* recWs  = (double*)w; w += (size_t)8192 * 8;           // 64 KB
  int*    flagWs = (int*)w;    w += (size_t)NSIG * 4;           // 128 KB

  k_pre<<<3072, 256, 0, stream>>>(D, DtD, DtDf, (float4*)coefOut);
  k_fused<<<NSIG / 16, 512, 0, stream>>>(z, D, DtD, DtDf, coefOut, idxWs, cWs,
                                         csumWs, flagWs);
  k_redo<<<NSIG / 16, 512, 0, stream>>>(z, D, DtD, flagWs, coefOut, idxWs, cWs,
                                        csumWs);
  k_zq<<<8192, 256, 0, stream>>>(z, D, idxWs, cWs, zqOut, recWs);
  k_loss<<<1, 256, 0, stream>>>(recWs, csumWs, lossOut);
}

// Round 17
// 249.842 us; speedup vs baseline: 5.2302x; 1.3579x over previous
//
#include <hip/hip_runtime.h>
#include <math.h>

#define NSIG 32768
#define KD   512
#define ED   64
#define SP   5

// ---------------- prologue: DtD(f64) + DtDf(f32) + zero coefOut ----------------
__global__ __launch_bounds__(256) void k_pre(const float* __restrict__ D,
                                             double* __restrict__ DtD,
                                             float* __restrict__ DtDf,
                                             float4* __restrict__ coef4) {
  if (blockIdx.x < 1024) {
    int flat = blockIdx.x * 256 + threadIdx.x;   // 0..262143
    int i = flat >> 9, j = flat & 511;
    double acc = 0.0;
    #pragma unroll
    for (int e = 0; e < ED; ++e)
      acc += (double)D[e * KD + i] * (double)D[e * KD + j];
    if (i == j) acc += 1e-10;
    DtD[flat] = acc;
    DtDf[flat] = (float)acc;
  } else {
    size_t count4 = (size_t)KD * NSIG / 4;
    size_t i = (size_t)(blockIdx.x - 1024) * 256 + threadIdx.x;
    size_t stride = (size_t)2048 * 256;
    float4 zv = make_float4(0.f, 0.f, 0.f, 0.f);
    for (; i < count4; i += stride) coef4[i] = zv;
  }
}

// ---------------- f64 OMP iteration (R11-exact; used by k_redo) ----------------
template <int K>
__device__ __forceinline__ void omp_iter64(const double* __restrict__ DtD,
                                           const double (&c0)[16], unsigned& amask,
                                           int (&idx)[SP], double (&cc)[SP],
                                           double (&tri)[15], double (&c0sel)[SP],
                                           int li) {
  double vb = -INFINITY;
  int ab = 0x7FFFFFFF;
  #pragma unroll
  for (int j4 = 0; j4 < 4; ++j4) {
    int a0 = (j4 << 7) + (li << 2);
    double v0 = c0[4 * j4], v1 = c0[4 * j4 + 1];
    double v2 = c0[4 * j4 + 2], v3 = c0[4 * j4 + 3];
    #pragma unroll
    for (int m = 0; m < K; ++m) {
      const double* gp = DtD + (size_t)idx[m] * KD + a0;
      double2 gA = *(const double2*)gp;
      double2 gB = *(const double2*)(gp + 2);
      v0 -= gA.x * cc[m];
      v1 -= gA.y * cc[m];
      v2 -= gB.x * cc[m];
      v3 -= gB.y * cc[m];
    }
    v0 = ((amask >> (4 * j4 + 0)) & 1u) ? -INFINITY : v0;
    v1 = ((amask >> (4 * j4 + 1)) & 1u) ? -INFINITY : v1;
    v2 = ((amask >> (4 * j4 + 2)) & 1u) ? -INFINITY : v2;
    v3 = ((amask >> (4 * j4 + 3)) & 1u) ? -INFINITY : v3;
    if (v0 > vb) { vb = v0; ab = a0; }
    if (v1 > vb) { vb = v1; ab = a0 + 1; }
    if (v2 > vb) { vb = v2; ab = a0 + 2; }
    if (v3 > vb) { vb = v3; ab = a0 + 3; }
  }
  #pragma unroll
  for (int s = 16; s >= 1; s >>= 1) {
    double ov = __shfl_xor(vb, s, 64);
    int    oa = __shfl_xor(ab, s, 64);
    if (ov > vb || (ov == vb && oa < ab)) { vb = ov; ab = oa; }
  }
  idx[K] = ab;
  if (((ab >> 2) & 31) == li) amask |= 1u << ((((ab >> 7) << 2)) | (ab & 3));
  const double* drow = DtD + (size_t)ab * KD;
  double bb[SP], u[SP];
  #pragma unroll
  for (int m = 0; m < K; ++m) bb[m] = drow[idx[m]];
  {
    double csel = vb;
    #pragma unroll
    for (int m = 0; m < K; ++m) csel += bb[m] * cc[m];
    c0sel[K] = csel;
  }
  double sch = drow[ab];
  #pragma unroll
  for (int i = 0; i < K; ++i) {
    double ui = 0.0;
    #pragma unroll
    for (int m = 0; m < K; ++m) {
      int lo = i < m ? i : m, hi = i < m ? m : i;
      ui += tri[lo * SP - lo * (lo + 1) / 2 + hi] * bb[m];
    }
    u[i] = ui;
    sch -= bb[i] * ui;
  }
  double r = 1.0 / sch;
  #pragma unroll
  for (int i = 0; i < K; ++i) {
    #pragma unroll
    for (int j = i; j < K; ++j) tri[i * SP - i * (i + 1) / 2 + j] += r * u[i] * u[j];
    tri[i * SP - i * (i + 1) / 2 + K] = -r * u[i];
  }
  tri[K * SP - K * (K + 1) / 2 + K] = r;
  double h[SP];
  #pragma unroll
  for (int i = 0; i <= K; ++i) {
    double s = 0.0;
    #pragma unroll
    for (int j = 0; j <= K; ++j) {
      int lo = i < j ? i : j, hi = i < j ? j : i;
      s += tri[lo * SP - lo * (lo + 1) / 2 + hi] * c0sel[j];
    }
    h[i] = s;
  }
  #pragma unroll
  for (int i = 0; i < K; ++i) cc[i] = h[i] - cc[i];
  cc[K] = h[K];
}

// ---------------- f32 OMP iteration with top-2 flag (fast path) ----------------
// f32 scan selects; near-ties (gap < tau) set redoFlag (resolved by k_redo).
// tau derived from the rigorous f32 error bound (R16 post-mortem):
//   |score err| <= gamma_63*||z|| + ~1.5e-6*ccmax <= 4e-5 + 1.5e-6*ccmax
//   gap err <= 8e-5 + 3e-6*ccmax ; tau = 2e-4 + 2e-5*ccmax (2.4x margin).
// c0sel[K] computed EXACTLY in f64 via 32-lane parallel reduce of D.z.
template <int K>
__device__ __forceinline__ void omp_iter32(const double* __restrict__ DtD,
                                           const float* __restrict__ DtDf,
                                           const float* __restrict__ Dg,
                                           const float* __restrict__ zbuf,
                                           int myS,
                                           const float (&c0f)[16], unsigned& amask,
                                           int (&idx)[SP], double (&cc)[SP],
                                           double (&tri)[15], double (&c0sel)[SP],
                                           int li, int& redoFlag) {
  float ccf[SP];
  #pragma unroll
  for (int m = 0; m < K; ++m) ccf[m] = (float)cc[m];
  // ----- f32 masked scan with per-lane top-2 -----
  float v1 = -INFINITY, v2 = -INFINITY;
  int a1 = 0x7FFFFFFF;
  #pragma unroll
  for (int j4 = 0; j4 < 4; ++j4) {
    int a0 = (j4 << 7) + (li << 2);
    float gv[SP][4];
    #pragma unroll
    for (int m = 0; m < K; ++m) {
      float4 q = *(const float4*)(DtDf + (size_t)idx[m] * KD + a0);
      gv[m][0] = q.x; gv[m][1] = q.y; gv[m][2] = q.z; gv[m][3] = q.w;
    }
    #pragma unroll
    for (int bit = 0; bit < 4; ++bit) {
      float v = c0f[4 * j4 + bit];
      #pragma unroll
      for (int m = 0; m < K; ++m) v -= gv[m][bit] * ccf[m];
      v = ((amask >> (4 * j4 + bit)) & 1u) ? -INFINITY : v;
      if (v > v1) { v2 = v1; v1 = v; a1 = a0 + bit; }   // ascending atoms:
      else v2 = fmaxf(v2, v);                           // strict > keeps smallest
    }
  }
  // ----- 32-lane top-2 merge (winner tie-break: smallest atom) -----
  #pragma unroll
  for (int s = 16; s >= 1; s >>= 1) {
    float ov1 = __shfl_xor(v1, s, 64);
    int   oa1 = __shfl_xor(a1, s, 64);
    float ov2 = __shfl_xor(v2, s, 64);
    bool oWins = (ov1 > v1) || (ov1 == v1 && oa1 < a1);
    float loserTop = oWins ? v1 : ov1;
    if (oWins) { v1 = ov1; a1 = oa1; }
    v2 = fmaxf(fmaxf(v2, ov2), loserTop);
  }
  float ccmax = 0.0f;
  #pragma unroll
  for (int m = 0; m < K; ++m) ccmax = fmaxf(ccmax, fabsf(ccf[m]));
  float tau = 2e-4f + 2e-5f * ccmax;     // bound-derived (see header comment)
  if (!(v1 - v2 >= tau)) redoFlag = 1;   // near-tie (or NaN) -> exact redo later
  int ab = a1;
  idx[K] = ab;
  if (((ab >> 2) & 31) == li) amask |= 1u << ((((ab >> 7) << 2)) | (ab & 3));
  // ----- exact f64 c0sel[K] = <D[:,ab], z[:,myS]> via parallel reduce -----
  {
    int e0 = li << 1;
    double part = (double)Dg[e0 * KD + ab] * (double)zbuf[e0 * 16 + myS]
                + (double)Dg[(e0 + 1) * KD + ab] * (double)zbuf[(e0 + 1) * 16 + myS];
    #pragma unroll
    for (int s = 16; s >= 1; s >>= 1) part += __shfl_xor(part, s, 64);
    c0sel[K] = part;
  }
  // ----- f64 Gram gather + Schur rank-1 + solve (unchanged) -----
  const double* drow = DtD + (size_t)ab * KD;
  double bb[SP], u[SP];
  #pragma unroll
  for (int m = 0; m < K; ++m) bb[m] = drow[idx[m]];
  double sch = drow[ab];
  #pragma unroll
  for (int i = 0; i < K; ++i) {
    double ui = 0.0;
    #pragma unroll
    for (int m = 0; m < K; ++m) {
      int lo = i < m ? i : m, hi = i < m ? m : i;
      ui += tri[lo * SP - lo * (lo + 1) / 2 + hi] * bb[m];
    }
    u[i] = ui;
    sch -= bb[i] * ui;
  }
  double r = 1.0 / sch;
  #pragma unroll
  for (int i = 0; i < K; ++i) {
    #pragma unroll
    for (int j = i; j < K; ++j) tri[i * SP - i * (i + 1) / 2 + j] += r * u[i] * u[j];
    tri[i * SP - i * (i + 1) / 2 + K] = -r * u[i];
  }
  tri[K * SP - K * (K + 1) / 2 + K] = r;
  double h[SP];
  #pragma unroll
  for (int i = 0; i <= K; ++i) {
    double s = 0.0;
    #pragma unroll
    for (int j = 0; j <= K; ++j) {
      int lo = i < j ? i : j, hi = i < j ? j : i;
      s += tri[lo * SP - lo * (lo + 1) / 2 + hi] * c0sel[j];
    }
    h[i] = s;
  }
  #pragma unroll
  for (int i = 0; i < K; ++i) cc[i] = h[i] - cc[i];
  cc[K] = h[K];
}

// ---------------- fused kernel: f32 corr + f32 scan + f64 solve ----------------
__global__ __launch_bounds__(512) void k_fused(const float* __restrict__ z,
                                               const float* __restrict__ D,
                                               const double* __restrict__ DtD,
                                               const float* __restrict__ DtDf,
                                               float* __restrict__ coefOut,
                                               int* __restrict__ idxWs,
                                               double* __restrict__ cWs,
                                               double* __restrict__ csumWs,
                                               int* __restrict__ flagWs) {
  __shared__ float Dlds[2][8 * 512];   // 2 x 16 KB double-buffered 8-row D tiles
  __shared__ float zbuf[64 * 16];      // 4 KB [e][sig]
  int tid = threadIdx.x;
  int lane = tid & 63;
  int wv = tid >> 6;                   // wave 0..7 -> signals 2wv, 2wv+1
  int li = lane & 31;
  int g  = lane >> 5;
  int myS = 2 * wv + g;
  int n = blockIdx.x * 16 + myS;
  {
    int n0 = blockIdx.x * 16;
    int b = n0 >> 10, p0 = n0 & 1023;
    const float* zb = z + (size_t)b * 65536 + p0;
    #pragma unroll
    for (int k2 = 0; k2 < 2; ++k2) {
      int f = tid + 512 * k2;
      zbuf[f] = zb[(f >> 4) * 1024 + (f & 15)];
    }
  }
  #pragma unroll
  for (int i = 0; i < 2; ++i) {
    const float* gp = D + i * 2048 + wv * 256 + lane * 4;
    float* lp = &Dlds[0][i * 2048 + wv * 256];
    __builtin_amdgcn_global_load_lds(
        (const __attribute__((address_space(1))) void*)gp,
        (__attribute__((address_space(3))) void*)lp, 16, 0, 0);
  }
  float cA[8], cB[8];
  #pragma unroll
  for (int p = 0; p < 8; ++p) { cA[p] = 0.0f; cB[p] = 0.0f; }
  for (int t8 = 0; t8 < 8; ++t8) {
    __syncthreads();
    if (t8 < 7) {
      #pragma unroll
      for (int i = 0; i < 2; ++i) {
        const float* gp = D + (t8 + 1) * 4096 + i * 2048 + wv * 256 + lane * 4;
        float* lp = &Dlds[(t8 + 1) & 1][i * 2048 + wv * 256];
        __builtin_amdgcn_global_load_lds(
            (const __attribute__((address_space(1))) void*)gp,
            (__attribute__((address_space(3))) void*)lp, 16, 0, 0);
      }
    }
    const float* buf = Dlds[t8 & 1];
    #pragma unroll
    for (int e = 0; e < 8; ++e) {
      float2 zz = *(const float2*)(zbuf + (t8 * 8 + e) * 16 + 2 * wv);
      float zA = zz.x, zB = zz.y;
      const float* drow = buf + e * 512;
      float4 d0 = *(const float4*)(drow + lane * 4);
      float4 d1 = *(const float4*)(drow + 256 + lane * 4);
      float dv[8] = {d0.x, d0.y, d0.z, d0.w, d1.x, d1.y, d1.z, d1.w};
      #pragma unroll
      for (int p = 0; p < 8; ++p) {
        cA[p] += zA * dv[p];
        cB[p] += zB * dv[p];
      }
    }
  }
  // corr -> scan layout exchange (f32)
  float c0f[16];
  #pragma unroll
  for (int j4 = 0; j4 < 4; ++j4) {
    int src = ((j4 & 1) << 5) + li;
    #pragma unroll
    for (int bit = 0; bit < 4; ++bit) {
      float tA = __shfl(cA[((j4 >> 1) << 2) + bit], src, 64);
      float tB = __shfl(cB[((j4 >> 1) << 2) + bit], src, 64);
      c0f[4 * j4 + bit] = g ? tB : tA;
    }
  }
  unsigned amask = 0;
  int redoFlag = 0;
  int idx[SP]; double cc[SP]; double tri[15]; double c0sel[SP];
  omp_iter32<0>(DtD, DtDf, D, zbuf, myS, c0f, amask, idx, cc, tri, c0sel, li, redoFlag);
  omp_iter32<1>(DtD, DtDf, D, zbuf, myS, c0f, amask, idx, cc, tri, c0sel, li, redoFlag);
  omp_iter32<2>(DtD, DtDf, D, zbuf, myS, c0f, amask, idx, cc, tri, c0sel, li, redoFlag);
  omp_iter32<3>(DtD, DtDf, D, zbuf, myS, c0f, amask, idx, cc, tri, c0sel, li, redoFlag);
  omp_iter32<4>(DtD, DtDf, D, zbuf, myS, c0f, amask, idx, cc, tri, c0sel, li, redoFlag);
  if (li == 0) {
    double cs = 0.0;
    #pragma unroll
    for (int j = 0; j < SP; ++j) {
      double cj = cc[j];
      cj = fmin(fmax(cj, -10000000.0), 10000000.0);   // COEFF_CLAMP
      cs += fabs(cj);
      idxWs[n * SP + j] = idx[j];
      cWs[n * SP + j] = cj;
      coefOut[(size_t)idx[j] * NSIG + n] = (float)cj;
    }
    csumWs[n] = cs;
    flagWs[n] = redoFlag;
  }
}

// ---------------- redo kernel: exact-f64 OMP for flagged signals ----------------
__global__ __launch_bounds__(512) void k_redo(const float* __restrict__ z,
                                              const float* __restrict__ D,
                                              const double* __restrict__ DtD,
                                              const int* __restrict__ flagWs,
                                              float* __restrict__ coefOut,
                                              int* __restrict__ idxWs,
                                              double* __restrict__ cWs,
                                              double* __restrict__ csumWs) {
  int tid = threadIdx.x;
  int lane = tid & 63;
  int wv = tid >> 6;
  int li = lane & 31;
  int g  = lane >> 5;
  int n = blockIdx.x * 16 + 2 * wv + g;
  if (!flagWs[n]) return;                 // group-uniform; exec-mask divergence ok
  int b = n >> 10, p = n & 1023;
  const float* zp = z + (size_t)b * 65536 + p;
  // exact f64 c0, e-ascending per atom (bit-identical to the R11 pipeline)
  double c0[16];
  #pragma unroll
  for (int j = 0; j < 16; ++j) c0[j] = 0.0;
  for (int e = 0; e < ED; ++e) {
    double zv = (double)zp[e * 1024];
    #pragma unroll
    for (int j4 = 0; j4 < 4; ++j4) {
      float4 dv = *(const float4*)(D + e * KD + (j4 << 7) + (li << 2));
      c0[4 * j4 + 0] += zv * (double)dv.x;
      c0[4 * j4 + 1] += zv * (double)dv.y;
      c0[4 * j4 + 2] += zv * (double)dv.z;
      c0[4 * j4 + 3] += zv * (double)dv.w;
    }
  }
  unsigned amask = 0;
  int idx[SP]; double cc[SP]; double tri[15]; double c0sel[SP];
  omp_iter64<0>(DtD, c0, amask, idx, cc, tri, c0sel, li);
  omp_iter64<1>(DtD, c0, amask, idx, cc, tri, c0sel, li);
  omp_iter64<2>(DtD, c0, amask, idx, cc, tri, c0sel, li);
  omp_iter64<3>(DtD, c0, amask, idx, cc, tri, c0sel, li);
  omp_iter64<4>(DtD, c0, amask, idx, cc, tri, c0sel, li);
  if (li == 0) {
    // zero the f32-pass writes, then write exact results
    #pragma unroll
    for (int j = 0; j < SP; ++j)
      coefOut[(size_t)idxWs[n * SP + j] * NSIG + n] = 0.0f;
    double cs = 0.0;
    #pragma unroll
    for (int j = 0; j < SP; ++j) {
      double cj = cc[j];
      cj = fmin(fmax(cj, -10000000.0), 10000000.0);
      cs += fabs(cj);
      idxWs[n * SP + j] = idx[j];
      cWs[n * SP + j] = cj;
      coefOut[(size_t)idx[j] * NSIG + n] = (float)cj;
    }
    csumWs[n] = cs;
  }
}

// ---------------- kernel D: z_q + per-block rec-loss partials ----------------
__global__ __launch_bounds__(256) void k_zq(const float* __restrict__ z,
                                            const float* __restrict__ D,
                                            const int* __restrict__ idxWs,
                                            const double* __restrict__ cWs,
                                            float* __restrict__ zqOut,
                                            double* __restrict__ recWs) {
  int t = threadIdx.x;
  size_t flat = (size_t)blockIdx.x * 256 + t;
  int b = (int)(flat >> 16);
  int e = (int)((flat >> 10) & 63);
  int p = (int)(flat & 1023);
  int n = b * 1024 + p;
  double u = 0.0;
  #pragma unroll
  for (int j = 0; j < SP; ++j) {
    int a = idxWs[n * SP + j];
    u += (double)D[e * KD + a] * cWs[n * SP + j];
  }
  float zv = z[flat];
  double d = u - (double)zv;
  double dc = fmin(fmax(d, -1.0), 1.0);
  zqOut[flat] = (float)((double)zv + dc);
  __shared__ double red[256];
  red[t] = d * d;
  __syncthreads();
  #pragma unroll
  for (int s = 128; s >= 1; s >>= 1) {
    if (t < s) red[t] += red[t + s];
    __syncthreads();
  }
  if (t == 0) recWs[blockIdx.x] = red[0];
}

// ---------------- kernel E: deterministic final reduction -> loss ----------------
__global__ __launch_bounds__(256) void k_loss(const double* __restrict__ recWs,
                                              const double* __restrict__ csumWs,
                                              float* __restrict__ lossOut) {
  int t = threadIdx.x;
  double r = 0.0, c = 0.0;
  for (int i = t; i < 8192; i += 256) r += recWs[i];
  for (int i = t; i < NSIG; i += 256) c += csumWs[i];
  __shared__ double red[512];
  red[t] = r; red[256 + t] = c;
  __syncthreads();
  #pragma unroll
  for (int s = 128; s >= 1; s >>= 1) {
    if (t < s) { red[t] += red[t + s]; red[256 + t] += red[256 + t + s]; }
    __syncthreads();
  }
  if (t == 0) {
    double rec = red[0] / (double)(64.0 * 32768.0);
    double cm  = red[256] / (double)(512.0 * 32768.0);
    double loss = rec + 0.375 * rec + 0.001 * cm;
    lossOut[0] = (float)loss;
  }
}

extern "C" void kernel_launch(void* const* d_in, const int* in_sizes, int n_in,
                              void* d_out, int out_size, void* d_ws, size_t ws_size,
                              hipStream_t stream) {
  const float* z = (const float*)d_in[0];       // (32,64,32,32)
  const float* D = (const float*)d_in[1];       // (64,512)
  float* out = (float*)d_out;
  float* zqOut   = out;                         // 2097152
  float* lossOut = out + 2097152;               // 1
  float* coefOut = out + 2097153;               // 512*32768

  char* w = (char*)d_ws;
  double* DtD    = (double*)w; w += (size_t)KD * KD * 8;        // 2 MB
  float*  DtDf   = (float*)w;  w += (size_t)KD * KD * 4;        // 1 MB
  int*    idxWs  = (int*)w;    w += (size_t)NSIG * SP * 4;      // 640 KB
  double* cWs    = (double*)w; w += (size_t)NSIG * SP * 8;      // 1.25 MB
  double* csumWs = (double*)w; w += (size_t)NSIG * 8;           // 256 KB
  double* recWs  = (double*)w; w += (size_t)8192 * 8;           // 64 KB
  int*    flagWs = (int*)w;    w += (size_t)NSIG * 4;           // 128 KB

  k_pre<<<3072, 256, 0, stream>>>(D, DtD, DtDf, (float4*)coefOut);
  k_fused<<<NSIG / 16, 512, 0, stream>>>(z, D, DtD, DtDf, coefOut, idxWs, cWs,
                                         csumWs, flagWs);
  k_redo<<<NSIG / 16, 512, 0, stream>>>(z, D, DtD, flagWs, coefOut, idxWs, cWs,
                                        csumWs);
  k_zq<<<8192, 256, 0, stream>>>(z, D, idxWs, cWs, zqOut, recWs);
  k_loss<<<1, 256, 0, stream>>>(recWs, csumWs, lossOut);
}